// Round 4
// baseline (264.568 us; speedup 1.0000x reference)
//
#include <hip/hip_runtime.h>
#include <stdint.h>
#include <stddef.h>

// Problem constants (B, F, D) = (1024, 16, 64); P = 120
constexpr int NB = 1024;
constexpr int NF = 16;
constexpr int ND = 64;
constexpr int NP = 120;
constexpr int KD = ND * ND;          // 4096 contraction length per pair
constexpr int OUT_STRIDE = NP * ND;  // 7680 floats per batch row

using floatx4  = __attribute__((ext_vector_type(4))) float;
using short8   = __attribute__((ext_vector_type(8))) short;
using uint4v   = __attribute__((ext_vector_type(4))) uint32_t;
using ushort4v = __attribute__((ext_vector_type(4))) uint16_t;

constexpr int XT_STRIDE = 264;  // ushorts per xi^T row: 256 m + 8 pad (528 B, 16B-aligned)
constexpr int BT_STRIDE = 72;   // ushorts per W-tile row (144 B, 16B-aligned)
constexpr int BT_BUF    = ND * BT_STRIDE;  // 4608 ushorts per 64x64 W tile

// round-half-up f32->bf16 pair packed into one dword: low = bf16(f0), high = bf16(f1)
__device__ __forceinline__ uint32_t pack_bf16(float f0, float f1) {
    uint32_t u0 = __float_as_uint(f0) + 0x8000u;
    uint32_t u1 = __float_as_uint(f1) + 0x8000u;
    return __builtin_amdgcn_perm(u1, u0, 0x07060302u);
}
__device__ __forceinline__ uint16_t to_bf16(float f) {
    return (uint16_t)((__float_as_uint(f) + 0x8000u) >> 16);
}
__device__ __forceinline__ float from_bf16(uint16_t u) {
    return __uint_as_float(((uint32_t)u) << 16);
}

// pack 16 fp32 (one W row-chunk) to bf16 and store 32 B to LDS
__device__ __forceinline__ void pack_store(uint16_t* bd, const floatx4* wr) {
    uint4v q0 = (uint4v){ pack_bf16(wr[0].x, wr[0].y), pack_bf16(wr[0].z, wr[0].w),
                          pack_bf16(wr[1].x, wr[1].y), pack_bf16(wr[1].z, wr[1].w) };
    uint4v q1 = (uint4v){ pack_bf16(wr[2].x, wr[2].y), pack_bf16(wr[2].z, wr[2].w),
                          pack_bf16(wr[3].x, wr[3].y), pack_bf16(wr[3].z, wr[3].w) };
    *(uint4v*)(bd)     = q0;
    *(uint4v*)(bd + 8) = q1;
}

__global__ __launch_bounds__(256, 2)
void outer_kernel(const float* __restrict__ x, const float* __restrict__ W,
                  const float* __restrict__ bias, float* __restrict__ out)
{
    __shared__ uint16_t lds_xit[ND * XT_STRIDE];     // xi^T bf16: 33,792 B
    __shared__ uint16_t lds_bt[2][2][BT_BUF];        // W tiles: [dbuf][substep]: 36,864 B
    // total 70,656 B -> 2 blocks/CU

    const int p  = blockIdx.x;        // pair 0..119
    const int b0 = blockIdx.y * 256;  // batch tile origin

    // triu_indices(16, k=1) order
    int icol = 0, rem = p;
    while (rem >= NF - 1 - icol) { rem -= NF - 1 - icol; ++icol; }
    const int jcol = icol + 1 + rem;

    const int t    = threadIdx.x;
    const int wave = t >> 6;
    const int lane = t & 63;
    const int r    = lane & 15;
    const int quad = lane >> 4;

    // ---- stage xi transposed: lds_xit[a*XT_STRIDE + m] = bf16(x[b0+m][icol][a]) ----
    {
        const float* src = x + (size_t)(b0 + t) * (NF * ND) + icol * ND;
        #pragma unroll
        for (int c = 0; c < ND; c += 4) {
            floatx4 v = *(const floatx4*)(src + c);
            lds_xit[(c + 0) * XT_STRIDE + t] = to_bf16(v.x);
            lds_xit[(c + 1) * XT_STRIDE + t] = to_bf16(v.y);
            lds_xit[(c + 2) * XT_STRIDE + t] = to_bf16(v.z);
            lds_xit[(c + 3) * XT_STRIDE + t] = to_bf16(v.w);
        }
    }

    // ---- loop-invariant A-fragments: bf16(xj) in MFMA A layout (16x16x32) ----
    short8 afrag[4][2];
    #pragma unroll
    for (int ms = 0; ms < 4; ++ms) {
        const float* srow = x + (size_t)(b0 + wave*64 + ms*16 + r) * (NF * ND)
                              + jcol * ND + quad * 8;
        #pragma unroll
        for (int ks = 0; ks < 2; ++ks) {
            floatx4 v0 = *(const floatx4*)(srow + ks * 32);
            floatx4 v1 = *(const floatx4*)(srow + ks * 32 + 4);
            union { short8 s; uint32_t u[4]; } af;
            af.u[0] = pack_bf16(v0.x, v0.y);
            af.u[1] = pack_bf16(v0.z, v0.w);
            af.u[2] = pack_bf16(v1.x, v1.y);
            af.u[3] = pack_bf16(v1.z, v1.w);
            afrag[ms][ks] = af.s;
        }
    }

    // ---- W staging: thread covers (n_st, c_st..c_st+15) of each 64x64 a-tile ----
    const int n_st = t >> 2;
    const int c_st = (t & 3) * 16;
    const float* wsrc = W + ((size_t)p * ND + n_st) * KD + c_st;
    const int woff = n_st * BT_STRIDE + c_st;

    floatx4 wreg[8];

    // prologue: stage W(0), W(1) into buf0; prefetch W(2), W(3)
    #pragma unroll
    for (int q = 0; q < 4; ++q) wreg[q] = *(const floatx4*)(wsrc + q * 4);
    pack_store(&lds_bt[0][0][woff], &wreg[0]);
    #pragma unroll
    for (int q = 0; q < 4; ++q) wreg[q] = *(const floatx4*)(wsrc + ND + q * 4);
    pack_store(&lds_bt[0][1][woff], &wreg[0]);
    #pragma unroll
    for (int q = 0; q < 4; ++q) wreg[q]     = *(const floatx4*)(wsrc + 2 * ND + q * 4);
    #pragma unroll
    for (int q = 0; q < 4; ++q) wreg[4 + q] = *(const floatx4*)(wsrc + 3 * ND + q * 4);
    __syncthreads();

    floatx4 acc[4][4] = {};
    const floatx4 zerof = (floatx4){0.f, 0.f, 0.f, 0.f};

    // one a-sub-step: S_a = xj @ W_a^T, acc += xi[:,a] * S_a
    auto compute_step = [&](int a, const uint16_t* rbuf) {
        float xiv[4][4];
        #pragma unroll
        for (int ms = 0; ms < 4; ++ms) {
            ushort4v xu = *(const ushort4v*)&lds_xit[a * XT_STRIDE
                                                     + wave*64 + ms*16 + quad*4];
            xiv[ms][0] = from_bf16(xu.x);
            xiv[ms][1] = from_bf16(xu.y);
            xiv[ms][2] = from_bf16(xu.z);
            xiv[ms][3] = from_bf16(xu.w);
        }
        #pragma unroll
        for (int ns = 0; ns < 4; ++ns) {
            const int brow = (ns*16 + r) * BT_STRIDE + quad * 8;
            short8 bf0 = *(const short8*)&rbuf[brow];
            short8 bf1 = *(const short8*)&rbuf[brow + 32];
            #pragma unroll
            for (int ms = 0; ms < 4; ++ms) {
                floatx4 tv = __builtin_amdgcn_mfma_f32_16x16x32_bf16(
                    afrag[ms][0], bf0, zerof, 0, 0, 0);
                tv = __builtin_amdgcn_mfma_f32_16x16x32_bf16(
                    afrag[ms][1], bf1, tv, 0, 0, 0);
                #pragma unroll
                for (int reg = 0; reg < 4; ++reg)
                    acc[ms][ns][reg] = __builtin_fmaf(xiv[ms][reg], tv[reg],
                                                      acc[ms][ns][reg]);
            }
        }
    };

    #pragma unroll 1
    for (int t2 = 0; t2 < ND / 2; ++t2) {
        const int cur = t2 & 1;

        // (1) drain wreg (W(2t2+2), W(2t2+3), loaded last iter) into the other buffer
        if (t2 < ND/2 - 1) {
            pack_store(&lds_bt[cur ^ 1][0][woff], &wreg[0]);
            pack_store(&lds_bt[cur ^ 1][1][woff], &wreg[4]);
        }
        // (2) issue global prefetch of W(2t2+4), W(2t2+5) — 2-step flight window
        if (t2 < ND/2 - 2) {
            const float* wn = wsrc + (size_t)(2*t2 + 4) * ND;
            #pragma unroll
            for (int q = 0; q < 4; ++q) wreg[q]     = *(const floatx4*)(wn + q * 4);
            #pragma unroll
            for (int q = 0; q < 4; ++q) wreg[4 + q] = *(const floatx4*)(wn + ND + q * 4);
        }
        // (3) 64 MFMAs between barriers (2 a-steps)
        compute_step(2*t2,     &lds_bt[cur][0][0]);
        compute_step(2*t2 + 1, &lds_bt[cur][1][0]);
        // (4) single barrier per 2 a-steps
        __syncthreads();
    }

    // ---- epilogue: bias + store. C/D: col = lane&15, row = quad*4 + reg ----
    #pragma unroll
    for (int ns = 0; ns < 4; ++ns) {
        const float bb = bias[p * ND + ns*16 + r];
        #pragma unroll
        for (int ms = 0; ms < 4; ++ms) {
            #pragma unroll
            for (int reg = 0; reg < 4; ++reg) {
                const int row = b0 + wave*64 + ms*16 + quad*4 + reg;
                out[(size_t)row * OUT_STRIDE + p * ND + ns*16 + r]
                    = acc[ms][ns][reg] + bb;
            }
        }
    }
}

extern "C" void kernel_launch(void* const* d_in, const int* in_sizes, int n_in,
                              void* d_out, int out_size, void* d_ws, size_t ws_size,
                              hipStream_t stream) {
    const float* x    = (const float*)d_in[0];  // (1024, 16, 64)
    const float* W    = (const float*)d_in[1];  // (120, 64, 4096)
    const float* bias = (const float*)d_in[2];  // (120, 64)
    float* out = (float*)d_out;                 // (1024, 120, 64)

    dim3 grid(NP, NB / 256);   // 480 blocks; same-p blocks land on one XCD (120 % 8 == 0)
    outer_kernel<<<grid, 256, 0, stream>>>(x, W, bias, out);
}

// Round 5
// 226.029 us; speedup vs baseline: 1.1705x; 1.1705x over previous
//
#include <hip/hip_runtime.h>
#include <stdint.h>
#include <stddef.h>

// Problem constants (B, F, D) = (1024, 16, 64); P = 120
constexpr int NB = 1024;
constexpr int NF = 16;
constexpr int ND = 64;
constexpr int NP = 120;
constexpr int KD = ND * ND;          // 4096 contraction length per pair
constexpr int OUT_STRIDE = NP * ND;  // 7680 floats per batch row

using floatx4  = __attribute__((ext_vector_type(4))) float;
using short8   = __attribute__((ext_vector_type(8))) short;
using uint4v   = __attribute__((ext_vector_type(4))) uint32_t;
using uint2v   = __attribute__((ext_vector_type(2))) uint32_t;

constexpr int XT_STRIDE = 264;            // ushorts per xi^T row (528 B, 16B-aligned)
constexpr int BT_HALF   = 4096;           // ushorts per fragment-ordered 64x64 W tile (8 KB)

// round-half-up f32->bf16 pair packed into one dword: low = bf16(f0), high = bf16(f1)
__device__ __forceinline__ uint32_t pack_bf16(float f0, float f1) {
    uint32_t u0 = __float_as_uint(f0) + 0x8000u;
    uint32_t u1 = __float_as_uint(f1) + 0x8000u;
    return __builtin_amdgcn_perm(u1, u0, 0x07060302u);
}
__device__ __forceinline__ uint16_t to_bf16(float f) {
    return (uint16_t)((__float_as_uint(f) + 0x8000u) >> 16);
}

// pack 8 fp32 -> 8 bf16 (16 B) and store as one ds_write_b128
__device__ __forceinline__ void pack_store16(uint16_t* bd, floatx4 a, floatx4 b) {
    uint4v q = (uint4v){ pack_bf16(a.x, a.y), pack_bf16(a.z, a.w),
                         pack_bf16(b.x, b.y), pack_bf16(b.z, b.w) };
    *(uint4v*)(bd) = q;
}

__global__ __launch_bounds__(256, 2)
void outer_kernel(const float* __restrict__ x, const float* __restrict__ W,
                  const float* __restrict__ bias, float* __restrict__ out)
{
    __shared__ __align__(16) uint16_t lds_xit[ND * XT_STRIDE];  // 33,792 B
    __shared__ __align__(16) uint16_t lds_bt[2 * BT_HALF];      // 16,384 B (total 50,176)

    const int p  = blockIdx.x;        // pair 0..119
    const int b0 = blockIdx.y * 256;  // batch tile origin

    // triu_indices(16, k=1) order
    int icol = 0, rem = p;
    while (rem >= NF - 1 - icol) { rem -= NF - 1 - icol; ++icol; }
    const int jcol = icol + 1 + rem;

    const int t    = threadIdx.x;
    const int wave = t >> 6;
    const int lane = t & 63;
    const int r    = lane & 15;
    const int quad = lane >> 4;

    // ---- stage xi transposed: lds_xit[a*XT_STRIDE + m] = bf16(x[b0+m][icol][a]) ----
    {
        const float* src = x + (size_t)(b0 + t) * (NF * ND) + icol * ND;
        #pragma unroll
        for (int c = 0; c < ND; c += 4) {
            floatx4 v = *(const floatx4*)(src + c);
            lds_xit[(c + 0) * XT_STRIDE + t] = to_bf16(v.x);
            lds_xit[(c + 1) * XT_STRIDE + t] = to_bf16(v.y);
            lds_xit[(c + 2) * XT_STRIDE + t] = to_bf16(v.z);
            lds_xit[(c + 3) * XT_STRIDE + t] = to_bf16(v.w);
        }
    }

    // ---- loop-invariant A-fragments: bf16(xj) in MFMA A layout (16x16x32) ----
    short8 afrag[4][2];
    #pragma unroll
    for (int ms = 0; ms < 4; ++ms) {
        const float* srow = x + (size_t)(b0 + wave*64 + ms*16 + r) * (NF * ND)
                              + jcol * ND + quad * 8;
        #pragma unroll
        for (int ks = 0; ks < 2; ++ks) {
            floatx4 v0 = *(const floatx4*)(srow + ks * 32);
            floatx4 v1 = *(const floatx4*)(srow + ks * 32 + 4);
            union { short8 s; uint32_t u[4]; } af;
            af.u[0] = pack_bf16(v0.x, v0.y);
            af.u[1] = pack_bf16(v0.z, v0.w);
            af.u[2] = pack_bf16(v1.x, v1.y);
            af.u[3] = pack_bf16(v1.z, v1.w);
            afrag[ms][ks] = af.s;
        }
    }

    // ---- W staging, fragment-ordered tile ----
    // Frag index F = s*256 + t  (s = 0,1): decode ns = 2*s + (t>>7), ks = (t>>6)&1,
    // quad_w = (t>>4)&3, r_w = t&15.  Thread stores frag F at halfword F*8
    // (ds_write_b128 at lane*16 + const: conflict-free).  Element j of frag F is
    // Bt[ns*16 + r_w][ks*32 + quad_w*8 + j] = W[p*64 + n][a*64 + c0 + j].
    const int ks_w   = (t >> 6) & 1;
    const int quad_w = (t >> 4) & 3;
    const int r_w    = t & 15;
    const int c0_w   = ks_w * 32 + quad_w * 8;
    const int n0_w   = ((t >> 7) + 0) * 16 + r_w;      // s = 0
    const int n1_w   = ((t >> 7) + 2) * 16 + r_w;      // s = 1
    const float* wp0 = W + ((size_t)p * ND + n0_w) * KD + c0_w;
    const float* wp1 = W + ((size_t)p * ND + n1_w) * KD + c0_w;
    uint16_t* wst0 = &lds_bt[(size_t)t * 8];           // frag t      (buffer base +)
    uint16_t* wst1 = &lds_bt[(size_t)(256 + t) * 8];   // frag 256+t

    floatx4 wreg[4];

    // prologue: stage W(0) into buf0; prefetch W(1) into wreg
    wreg[0] = *(const floatx4*)(wp0);
    wreg[1] = *(const floatx4*)(wp0 + 4);
    wreg[2] = *(const floatx4*)(wp1);
    wreg[3] = *(const floatx4*)(wp1 + 4);
    pack_store16(wst0, wreg[0], wreg[1]);
    pack_store16(wst1, wreg[2], wreg[3]);
    wreg[0] = *(const floatx4*)(wp0 + ND);
    wreg[1] = *(const floatx4*)(wp0 + ND + 4);
    wreg[2] = *(const floatx4*)(wp1 + ND);
    wreg[3] = *(const floatx4*)(wp1 + ND + 4);
    __syncthreads();

    floatx4 acc[4][4] = {};
    const floatx4 zerof = (floatx4){0.f, 0.f, 0.f, 0.f};
    const uint16_t* rb_lane = lds_bt + (size_t)lane * 8;  // B-frag read base (per lane)

    #pragma unroll 1
    for (int a = 0; a < ND; ++a) {
        const int cur = a & 1;
        const uint16_t* rbuf = rb_lane + cur * BT_HALF;   // tile W(a), frag-ordered

        // xi for this a, rows matching C-frag rows (quad*4 + reg), as floatx4
        floatx4 xiv[4];
        #pragma unroll
        for (int ms = 0; ms < 4; ++ms) {
            uint2v xu = *(const uint2v*)&lds_xit[a * XT_STRIDE
                                                 + wave*64 + ms*16 + quad*4];
            xiv[ms] = (floatx4){ __uint_as_float(xu.x << 16),
                                 __uint_as_float(xu.x & 0xffff0000u),
                                 __uint_as_float(xu.y << 16),
                                 __uint_as_float(xu.y & 0xffff0000u) };
        }

        // S_a = xj @ W_a^T per subtile; acc += xi[:,a] * S_a
        #pragma unroll
        for (int ns = 0; ns < 4; ++ns) {
            short8 bf0 = *(const short8*)(rbuf + (ns*2 + 0) * 512);
            short8 bf1 = *(const short8*)(rbuf + (ns*2 + 1) * 512);
            #pragma unroll
            for (int ms = 0; ms < 4; ++ms) {
                floatx4 tv = __builtin_amdgcn_mfma_f32_16x16x32_bf16(
                    afrag[ms][0], bf0, zerof, 0, 0, 0);
                tv = __builtin_amdgcn_mfma_f32_16x16x32_bf16(
                    afrag[ms][1], bf1, tv, 0, 0, 0);
                acc[ms][ns] += xiv[ms] * tv;   // v_pk_fma_f32 x2
            }
        }

        // pack W(a+1) (in wreg, loaded last iter) into the other buffer
        if (a + 1 < ND) {
            uint16_t* bd0 = wst0 + (cur ^ 1) * BT_HALF;
            uint16_t* bd1 = wst1 + (cur ^ 1) * BT_HALF;
            pack_store16(bd0, wreg[0], wreg[1]);
            pack_store16(bd1, wreg[2], wreg[3]);
        }
        // prefetch W(a+2) — stays in flight across the barrier below
        if (a + 2 < ND) {
            const float* s0 = wp0 + (size_t)(a + 2) * ND;
            const float* s1 = wp1 + (size_t)(a + 2) * ND;
            wreg[0] = *(const floatx4*)(s0);
            wreg[1] = *(const floatx4*)(s0 + 4);
            wreg[2] = *(const floatx4*)(s1);
            wreg[3] = *(const floatx4*)(s1 + 4);
        }

        // lgkm-only barrier: ds_writes visible, global prefetch NOT drained
        asm volatile("" ::: "memory");
        __builtin_amdgcn_s_waitcnt(0xC07F);   // vmcnt(63) expcnt(7) lgkmcnt(0)
        __builtin_amdgcn_s_barrier();
        asm volatile("" ::: "memory");
    }

    // ---- epilogue: bias + store. C/D: col = lane&15, row = quad*4 + reg ----
    #pragma unroll
    for (int ns = 0; ns < 4; ++ns) {
        const float bb = bias[p * ND + ns*16 + r];
        #pragma unroll
        for (int ms = 0; ms < 4; ++ms) {
            #pragma unroll
            for (int reg = 0; reg < 4; ++reg) {
                const int row = b0 + wave*64 + ms*16 + quad*4 + reg;
                out[(size_t)row * OUT_STRIDE + p * ND + ns*16 + r]
                    = acc[ms][ns][reg] + bb;
            }
        }
    }
}

extern "C" void kernel_launch(void* const* d_in, const int* in_sizes, int n_in,
                              void* d_out, int out_size, void* d_ws, size_t ws_size,
                              hipStream_t stream) {
    const float* x    = (const float*)d_in[0];  // (1024, 16, 64)
    const float* W    = (const float*)d_in[1];  // (120, 64, 4096)
    const float* bias = (const float*)d_in[2];  // (120, 64)
    float* out = (float*)d_out;                 // (1024, 120, 64)

    dim3 grid(NP, NB / 256);   // 480 blocks; same-p blocks land on one XCD (120 % 8 == 0)
    outer_kernel<<<grid, 256, 0, stream>>>(x, W, bias, out);
}